// Round 2
// baseline (1897.997 us; speedup 1.0000x reference)
//
#include <hip/hip_runtime.h>
#include <math.h>

// Swin block: B=128, H=W=56, C=96, WS=7, SS=3, NH=3, N=49, NW=64, HD=32
#define HW_    3136
#define C_     96
#define SCALE_ 0.17677669529663687f

__device__ __forceinline__ float gelu_exact(float t) {
    return 0.5f * t * (1.0f + erff(t * 0.70710678118654752f));
}

// ---------------------------------------------------------------------------
// K1: per-window fused attention: gather(roll+partition) -> LN1 -> QKV ->
//     register attention (scores+softmax+PV fused, 1 thread per (head,row)) ->
//     proj -> +residual -> scatter
// grid = B*NW = 8192 blocks, 256 threads. LDS ~79 KB -> 2 blocks/CU.
// ---------------------------------------------------------------------------
__global__ __launch_bounds__(256) void k_attn(
    const float* __restrict__ x,
    const float* __restrict__ g1, const float* __restrict__ b1,
    const float* __restrict__ qw, const float* __restrict__ qb,
    const float* __restrict__ rpb,
    const float* __restrict__ pw, const float* __restrict__ pb,
    float* __restrict__ out)
{
    __shared__ __align__(16) float xn[49][100];     // LN'd input; reused as attn-out
    __shared__ __align__(16) float qkvs[49][292];   // q[0:96) k[96:192) v[192:288)
    __shared__ float rpb_lds[507];                  // 169 x 3 rel-pos bias
    __shared__ int tok[49];
    __shared__ int lbl[49];

    const int tid = threadIdx.x;
    const int blk = blockIdx.x;
    const int b   = blk >> 6;
    const int wi  = blk & 63;
    const int wh  = wi >> 3, ww = wi & 7;

    // phase 0: token map (shifted-window -> original position) + mask labels
    if (tid < 49) {
        int ih = tid / 7, iw = tid - ih * 7;
        int hs = wh * 7 + ih, ws = ww * 7 + iw;       // shifted-frame coords
        int h0 = hs + 3; if (h0 >= 56) h0 -= 56;      // original coords
        int w0 = ws + 3; if (w0 >= 56) w0 -= 56;
        tok[tid] = h0 * 56 + w0;
        int lh = (hs < 49) ? 0 : ((hs < 53) ? 1 : 2);
        int lw = (ws < 49) ? 0 : ((ws < 53) ? 1 : 2);
        lbl[tid] = lh * 3 + lw;
    }
    for (int idx = tid; idx < 507; idx += 256) rpb_lds[idx] = rpb[idx];
    __syncthreads();

    // phase 1: gather x rows
    const float* xb = x + (size_t)b * (HW_ * C_);
    for (int idx = tid; idx < 49 * 96; idx += 256) {
        int n = idx / 96, c = idx - n * 96;
        xn[n][c] = xb[(size_t)tok[n] * 96 + c];
    }
    __syncthreads();

    // phase 2: LN1 — 4 lanes per row (196 lanes), shfl_xor reduce
    if (tid < 196) {
        const int row = tid >> 2, qq = tid & 3;
        const int k0 = qq * 24;
        float sum = 0.f, sq = 0.f;
#pragma unroll
        for (int k = 0; k < 24; ++k) {
            float t = xn[row][k0 + k];
            sum += t; sq += t * t;
        }
        sum += __shfl_xor(sum, 1); sq += __shfl_xor(sq, 1);
        sum += __shfl_xor(sum, 2); sq += __shfl_xor(sq, 2);
        const float m = sum * (1.f / 96.f);
        const float var = sq * (1.f / 96.f) - m * m;
        const float r = rsqrtf(var + 1e-5f);
#pragma unroll
        for (int k = 0; k < 24; ++k) {
            const int c = k0 + k;
            xn[row][c] = (xn[row][c] - m) * r * g1[c] + b1[c];
        }
    }
    __syncthreads();

    // phase 3: QKV = xn(49x96) @ qw(96x288) + qb ; q *= SCALE
    // 7 rows x 8 cols per thread -> 252 tasks
    if (tid < 252) {
        const int ig = tid / 36;
        const int cg = tid - ig * 36;
        const int r0 = ig * 7;
        const int c0 = cg * 8;
        float acc[7][8];
#pragma unroll
        for (int r = 0; r < 7; ++r)
#pragma unroll
            for (int c = 0; c < 8; ++c) acc[r][c] = 0.f;
#pragma unroll 2
        for (int kk = 0; kk < 96; kk += 4) {
            float4 w0[4], w1_[4];
#pragma unroll
            for (int k2 = 0; k2 < 4; ++k2) {
                const float* wp = qw + (kk + k2) * 288 + c0;
                w0[k2]  = *reinterpret_cast<const float4*>(wp);
                w1_[k2] = *reinterpret_cast<const float4*>(wp + 4);
            }
#pragma unroll
            for (int r = 0; r < 7; ++r) {
                float4 a4 = *reinterpret_cast<const float4*>(&xn[r0 + r][kk]);
                float aa[4] = {a4.x, a4.y, a4.z, a4.w};
#pragma unroll
                for (int k2 = 0; k2 < 4; ++k2) {
                    acc[r][0] += aa[k2] * w0[k2].x;
                    acc[r][1] += aa[k2] * w0[k2].y;
                    acc[r][2] += aa[k2] * w0[k2].z;
                    acc[r][3] += aa[k2] * w0[k2].w;
                    acc[r][4] += aa[k2] * w1_[k2].x;
                    acc[r][5] += aa[k2] * w1_[k2].y;
                    acc[r][6] += aa[k2] * w1_[k2].z;
                    acc[r][7] += aa[k2] * w1_[k2].w;
                }
            }
        }
        const bool isq = (c0 < 96);   // col group never straddles 96
#pragma unroll
        for (int r = 0; r < 7; ++r)
#pragma unroll
            for (int c = 0; c < 8; ++c) {
                float v = acc[r][c] + qb[c0 + c];
                if (isq) v *= SCALE_;
                qkvs[r0 + r][c0 + c] = v;
            }
    }
    __syncthreads();

    // phase 4: fused attention — one thread per (head, row): scores in regs,
    // softmax in regs, PV accumulate; write attn-out into xn.
    if (tid < 147) {
        const int h = tid / 49, i = tid - h * 49;
        const int ih = i / 7, iw = i - ih * 7;
        const int qoff = h * 32, koff = 96 + h * 32, voff = 192 + h * 32;
        const int mylbl = lbl[i];

        float4 q4[8];
#pragma unroll
        for (int dd = 0; dd < 8; ++dd)
            q4[dd] = *reinterpret_cast<const float4*>(&qkvs[i][qoff + dd * 4]);

        float s[49];
#pragma unroll
        for (int j = 0; j < 49; ++j) {
            float acc = 0.f;
#pragma unroll
            for (int dd = 0; dd < 8; ++dd) {
                float4 k4 = *reinterpret_cast<const float4*>(&qkvs[j][koff + dd * 4]);
                acc += q4[dd].x * k4.x + q4[dd].y * k4.y
                     + q4[dd].z * k4.z + q4[dd].w * k4.w;
            }
            const int jh = j / 7, jw = j - jh * 7;
            const int ridx = (ih - jh + 6) * 13 + (iw - jw + 6);
            acc += rpb_lds[ridx * 3 + h];
            if (mylbl != lbl[j]) acc -= 100.f;
            s[j] = acc;
        }

        float mx = -1e30f;
#pragma unroll
        for (int j = 0; j < 49; ++j) mx = fmaxf(mx, s[j]);
        float sum = 0.f;
#pragma unroll
        for (int j = 0; j < 49; ++j) { float e = __expf(s[j] - mx); s[j] = e; sum += e; }
        const float inv = 1.f / sum;
#pragma unroll
        for (int j = 0; j < 49; ++j) s[j] *= inv;

        float4 o[8];
#pragma unroll
        for (int dd = 0; dd < 8; ++dd) o[dd] = make_float4(0.f, 0.f, 0.f, 0.f);
#pragma unroll
        for (int j = 0; j < 49; ++j) {
            const float sv = s[j];
#pragma unroll
            for (int dd = 0; dd < 8; ++dd) {
                float4 v4 = *reinterpret_cast<const float4*>(&qkvs[j][voff + dd * 4]);
                o[dd].x += sv * v4.x; o[dd].y += sv * v4.y;
                o[dd].z += sv * v4.z; o[dd].w += sv * v4.w;
            }
        }
#pragma unroll
        for (int dd = 0; dd < 8; ++dd)
            *reinterpret_cast<float4*>(&xn[i][h * 32 + dd * 4]) = o[dd];
    }
    __syncthreads();

    // phase 5: proj + residual, scatter back to original token order
    // 7 rows x 4 cols per task, 168 tasks
    if (tid < 168) {
        const int ig = tid / 24, cg = tid - ig * 24;
        const int r0 = ig * 7, c0 = cg * 4;
        float acc[7][4];
#pragma unroll
        for (int r = 0; r < 7; ++r)
#pragma unroll
            for (int c = 0; c < 4; ++c) acc[r][c] = 0.f;
#pragma unroll 2
        for (int kk = 0; kk < 96; kk += 4) {
            float4 w[4];
#pragma unroll
            for (int k2 = 0; k2 < 4; ++k2)
                w[k2] = *reinterpret_cast<const float4*>(&pw[(kk + k2) * 96 + c0]);
#pragma unroll
            for (int r = 0; r < 7; ++r) {
                float4 a4 = *reinterpret_cast<const float4*>(&xn[r0 + r][kk]);
                float aa[4] = {a4.x, a4.y, a4.z, a4.w};
#pragma unroll
                for (int k2 = 0; k2 < 4; ++k2) {
                    acc[r][0] += aa[k2] * w[k2].x;
                    acc[r][1] += aa[k2] * w[k2].y;
                    acc[r][2] += aa[k2] * w[k2].z;
                    acc[r][3] += aa[k2] * w[k2].w;
                }
            }
        }
        float* ob = out + (size_t)b * (HW_ * C_);
#pragma unroll
        for (int r = 0; r < 7; ++r) {
            const int n = r0 + r;
            const int t = tok[n];
            const float* resid = xb + (size_t)t * 96 + c0;
            float* op = ob + (size_t)t * 96 + c0;
#pragma unroll
            for (int c = 0; c < 4; ++c)
                op[c] = acc[r][c] + pb[c0 + c] + resid[c];
        }
    }
}

// ---------------------------------------------------------------------------
// K2: fused MLP, in-place on d_out: LN2 -> fc1 + gelu(exact) -> fc2 + residual
// 32 rows per block, grid = 401408/32 = 12544 blocks, 256 threads
// ---------------------------------------------------------------------------
__global__ __launch_bounds__(256) void k_mlp(
    const float* __restrict__ io_in,
    const float* __restrict__ g2, const float* __restrict__ b2,
    const float* __restrict__ w1, const float* __restrict__ bb1,
    const float* __restrict__ w2, const float* __restrict__ bb2,
    float* __restrict__ io_out)
{
    __shared__ __align__(16) float xr[32][100];   // raw rows (residual)
    __shared__ __align__(16) float xl[32][100];   // LN'd rows
    __shared__ __align__(16) float hs[32][388];   // gelu(fc1) activations

    const int tid = threadIdx.x;
    const size_t row0 = (size_t)blockIdx.x * 32;

    for (int idx = tid; idx < 32 * 96; idx += 256) {
        int n = idx / 96, c = idx - n * 96;
        xr[n][c] = io_in[(row0 + n) * 96 + c];
    }
    __syncthreads();

    // LN2 — 4 lanes per row (128 lanes), shfl_xor reduce
    if (tid < 128) {
        const int row = tid >> 2, qq = tid & 3;
        const int k0 = qq * 24;
        float sum = 0.f, sq = 0.f;
#pragma unroll
        for (int k = 0; k < 24; ++k) {
            float t = xr[row][k0 + k];
            sum += t; sq += t * t;
        }
        sum += __shfl_xor(sum, 1); sq += __shfl_xor(sq, 1);
        sum += __shfl_xor(sum, 2); sq += __shfl_xor(sq, 2);
        const float m = sum * (1.f / 96.f);
        const float var = sq * (1.f / 96.f) - m * m;
        const float r = rsqrtf(var + 1e-5f);
#pragma unroll
        for (int k = 0; k < 24; ++k) {
            const int c = k0 + k;
            xl[row][c] = (xr[row][c] - m) * r * g2[c] + b2[c];
        }
    }
    __syncthreads();

    // fc1 + gelu: (32x96) @ (96x384); 8 rows x 8 cols per thread -> 192 tasks
    if (tid < 192) {
        const int ig = tid / 48, cg = tid - ig * 48;
        const int r0 = ig * 8, c0 = cg * 8;
        float acc[8][8];
#pragma unroll
        for (int r = 0; r < 8; ++r)
#pragma unroll
            for (int c = 0; c < 8; ++c) acc[r][c] = 0.f;
#pragma unroll 2
        for (int kk = 0; kk < 96; kk += 4) {
            float4 wA[4], wB[4];
#pragma unroll
            for (int k2 = 0; k2 < 4; ++k2) {
                const float* wp = w1 + (kk + k2) * 384 + c0;
                wA[k2] = *reinterpret_cast<const float4*>(wp);
                wB[k2] = *reinterpret_cast<const float4*>(wp + 4);
            }
#pragma unroll
            for (int r = 0; r < 8; ++r) {
                float4 a4 = *reinterpret_cast<const float4*>(&xl[r0 + r][kk]);
                float aa[4] = {a4.x, a4.y, a4.z, a4.w};
#pragma unroll
                for (int k2 = 0; k2 < 4; ++k2) {
                    acc[r][0] += aa[k2] * wA[k2].x;
                    acc[r][1] += aa[k2] * wA[k2].y;
                    acc[r][2] += aa[k2] * wA[k2].z;
                    acc[r][3] += aa[k2] * wA[k2].w;
                    acc[r][4] += aa[k2] * wB[k2].x;
                    acc[r][5] += aa[k2] * wB[k2].y;
                    acc[r][6] += aa[k2] * wB[k2].z;
                    acc[r][7] += aa[k2] * wB[k2].w;
                }
            }
        }
#pragma unroll
        for (int r = 0; r < 8; ++r)
#pragma unroll
            for (int c = 0; c < 8; ++c)
                hs[r0 + r][c0 + c] = gelu_exact(acc[r][c] + bb1[c0 + c]);
    }
    __syncthreads();

    // fc2 + residual: (32x384) @ (384x96); 4 rows x 4 cols per thread -> 192 tasks
    if (tid < 192) {
        const int ig = tid / 24, cg = tid - ig * 24;
        const int r0 = ig * 4, c0 = cg * 4;
        float acc[4][4];
#pragma unroll
        for (int r = 0; r < 4; ++r)
#pragma unroll
            for (int c = 0; c < 4; ++c) acc[r][c] = 0.f;
#pragma unroll 2
        for (int kk = 0; kk < 384; kk += 4) {
            float4 w[4];
#pragma unroll
            for (int k2 = 0; k2 < 4; ++k2)
                w[k2] = *reinterpret_cast<const float4*>(&w2[(kk + k2) * 96 + c0]);
#pragma unroll
            for (int r = 0; r < 4; ++r) {
                float4 a4 = *reinterpret_cast<const float4*>(&hs[r0 + r][kk]);
                float aa[4] = {a4.x, a4.y, a4.z, a4.w};
#pragma unroll
                for (int k2 = 0; k2 < 4; ++k2) {
                    acc[r][0] += aa[k2] * w[k2].x;
                    acc[r][1] += aa[k2] * w[k2].y;
                    acc[r][2] += aa[k2] * w[k2].z;
                    acc[r][3] += aa[k2] * w[k2].w;
                }
            }
        }
#pragma unroll
        for (int r = 0; r < 4; ++r) {
            const int n = r0 + r;
#pragma unroll
            for (int c = 0; c < 4; ++c)
                io_out[(row0 + n) * 96 + c0 + c] = acc[r][c] + bb2[c0 + c] + xr[n][c0 + c];
        }
    }
}

extern "C" void kernel_launch(void* const* d_in, const int* in_sizes, int n_in,
                              void* d_out, int out_size, void* d_ws, size_t ws_size,
                              hipStream_t stream) {
    const float* x   = (const float*)d_in[0];
    const float* g1  = (const float*)d_in[1];
    const float* b1  = (const float*)d_in[2];
    const float* qw  = (const float*)d_in[3];
    const float* qb  = (const float*)d_in[4];
    const float* rpb = (const float*)d_in[5];
    const float* pw  = (const float*)d_in[6];
    const float* pb  = (const float*)d_in[7];
    const float* g2  = (const float*)d_in[8];
    const float* b2  = (const float*)d_in[9];
    const float* w1  = (const float*)d_in[10];
    const float* bb1 = (const float*)d_in[11];
    const float* w2  = (const float*)d_in[12];
    const float* bb2 = (const float*)d_in[13];
    float* out = (float*)d_out;

    hipLaunchKernelGGL(k_attn, dim3(8192), dim3(256), 0, stream,
                       x, g1, b1, qw, qb, rpb, pw, pb, out);
    hipLaunchKernelGGL(k_mlp, dim3(12544), dim3(256), 0, stream,
                       out, g2, b2, w1, bb1, w2, bb2, out);
}

// Round 3
// 1086.213 us; speedup vs baseline: 1.7474x; 1.7474x over previous
//
#include <hip/hip_runtime.h>
#include <math.h>

// Swin block: B=128, H=W=56, C=96, WS=7, SS=3, NH=3, N=49, NW=64, HD=32
#define HW_    3136
#define C_     96
#define SCALE_ 0.17677669529663687f

typedef __bf16 bf16x8 __attribute__((ext_vector_type(8)));
typedef float  f32x4  __attribute__((ext_vector_type(4)));

__device__ __forceinline__ float gelu_exact(float t) {
    return 0.5f * t * (1.0f + erff(t * 0.70710678118654752f));
}

// Fast exact-gelu: Abramowitz-Stegun 7.1.26 erf approx, |abs err| <= 1.5e-7.
__device__ __forceinline__ float gelu_fast(float t) {
    const float z  = 0.70710678118654752f * t;
    const float az = fabsf(z);
    const float k  = __builtin_amdgcn_rcpf(fmaf(0.3275911f, az, 1.0f));
    float p = fmaf(1.061405429f, k, -1.453152027f);
    p = fmaf(p, k, 1.421413741f);
    p = fmaf(p, k, -0.284496736f);
    p = fmaf(p, k, 0.254829592f);
    p = p * k;
    const float e    = __expf(-z * z);
    const float erfa = 1.0f - p * e;          // erf(|z|)
    const float erfs = copysignf(erfa, z);
    return 0.5f * t * (1.0f + erfs);
}

// ---------------------------------------------------------------------------
// k_cvt: build MFMA-fragment-ordered bf16 copies of W1 (96x384) and W2 (384x96)
// in d_ws. Fragment element j of lane l for (kt,nt): W[kt*32+(l>>4)*8+j][nt*16+(l&15)]
// W1 frags: 3kt x 24nt x 64 lanes -> t in [0,4608); W2: 12kt x 6nt x 64 -> [0,4608)
// ---------------------------------------------------------------------------
__global__ __launch_bounds__(256) void k_cvt(
    const float* __restrict__ w1, const float* __restrict__ w2,
    __bf16* __restrict__ ws)
{
    const int t = blockIdx.x * 256 + threadIdx.x;
    if (t < 4608) {
        const int kt = t / (24 * 64);
        const int nt = (t / 64) % 24;
        const int l  = t & 63;
        const int kr = kt * 32 + (l >> 4) * 8;
        const int col = nt * 16 + (l & 15);
        bf16x8 v;
#pragma unroll
        for (int j = 0; j < 8; ++j) v[j] = (__bf16)w1[(kr + j) * 384 + col];
        *reinterpret_cast<bf16x8*>(ws + (size_t)t * 8) = v;
    } else if (t < 9216) {
        const int t2 = t - 4608;
        const int kt = t2 / (6 * 64);
        const int nt = (t2 / 64) % 6;
        const int l  = t2 & 63;
        const int kr = kt * 32 + (l >> 4) * 8;
        const int col = nt * 16 + (l & 15);
        bf16x8 v;
#pragma unroll
        for (int j = 0; j < 8; ++j) v[j] = (__bf16)w2[(kr + j) * 96 + col];
        *reinterpret_cast<bf16x8*>(ws + 36864 + (size_t)t2 * 8) = v;
    }
}

// ---------------------------------------------------------------------------
// K1: per-window fused attention (unchanged from round 1 — verified correct)
// ---------------------------------------------------------------------------
__global__ __launch_bounds__(256) void k_attn(
    const float* __restrict__ x,
    const float* __restrict__ g1, const float* __restrict__ b1,
    const float* __restrict__ qw, const float* __restrict__ qb,
    const float* __restrict__ rpb,
    const float* __restrict__ pw, const float* __restrict__ pb,
    float* __restrict__ out)
{
    __shared__ __align__(16) float xn[49][100];     // LN'd input; reused as attn-out
    __shared__ __align__(16) float qkvs[49][292];   // q[0:96) k[96:192) v[192:288)
    __shared__ float rpb_lds[507];                  // 169 x 3 rel-pos bias
    __shared__ int tok[49];
    __shared__ int lbl[49];

    const int tid = threadIdx.x;
    const int blk = blockIdx.x;
    const int b   = blk >> 6;
    const int wi  = blk & 63;
    const int wh  = wi >> 3, ww = wi & 7;

    if (tid < 49) {
        int ih = tid / 7, iw = tid - ih * 7;
        int hs = wh * 7 + ih, ws = ww * 7 + iw;
        int h0 = hs + 3; if (h0 >= 56) h0 -= 56;
        int w0 = ws + 3; if (w0 >= 56) w0 -= 56;
        tok[tid] = h0 * 56 + w0;
        int lh = (hs < 49) ? 0 : ((hs < 53) ? 1 : 2);
        int lw = (ws < 49) ? 0 : ((ws < 53) ? 1 : 2);
        lbl[tid] = lh * 3 + lw;
    }
    for (int idx = tid; idx < 507; idx += 256) rpb_lds[idx] = rpb[idx];
    __syncthreads();

    const float* xb = x + (size_t)b * (HW_ * C_);
    for (int idx = tid; idx < 49 * 96; idx += 256) {
        int n = idx / 96, c = idx - n * 96;
        xn[n][c] = xb[(size_t)tok[n] * 96 + c];
    }
    __syncthreads();

    if (tid < 196) {
        const int row = tid >> 2, qq = tid & 3;
        const int k0 = qq * 24;
        float sum = 0.f, sq = 0.f;
#pragma unroll
        for (int k = 0; k < 24; ++k) {
            float t = xn[row][k0 + k];
            sum += t; sq += t * t;
        }
        sum += __shfl_xor(sum, 1); sq += __shfl_xor(sq, 1);
        sum += __shfl_xor(sum, 2); sq += __shfl_xor(sq, 2);
        const float m = sum * (1.f / 96.f);
        const float var = sq * (1.f / 96.f) - m * m;
        const float r = rsqrtf(var + 1e-5f);
#pragma unroll
        for (int k = 0; k < 24; ++k) {
            const int c = k0 + k;
            xn[row][c] = (xn[row][c] - m) * r * g1[c] + b1[c];
        }
    }
    __syncthreads();

    if (tid < 252) {
        const int ig = tid / 36;
        const int cg = tid - ig * 36;
        const int r0 = ig * 7;
        const int c0 = cg * 8;
        float acc[7][8];
#pragma unroll
        for (int r = 0; r < 7; ++r)
#pragma unroll
            for (int c = 0; c < 8; ++c) acc[r][c] = 0.f;
#pragma unroll 2
        for (int kk = 0; kk < 96; kk += 4) {
            float4 w0[4], w1_[4];
#pragma unroll
            for (int k2 = 0; k2 < 4; ++k2) {
                const float* wp = qw + (kk + k2) * 288 + c0;
                w0[k2]  = *reinterpret_cast<const float4*>(wp);
                w1_[k2] = *reinterpret_cast<const float4*>(wp + 4);
            }
#pragma unroll
            for (int r = 0; r < 7; ++r) {
                float4 a4 = *reinterpret_cast<const float4*>(&xn[r0 + r][kk]);
                float aa[4] = {a4.x, a4.y, a4.z, a4.w};
#pragma unroll
                for (int k2 = 0; k2 < 4; ++k2) {
                    acc[r][0] += aa[k2] * w0[k2].x;
                    acc[r][1] += aa[k2] * w0[k2].y;
                    acc[r][2] += aa[k2] * w0[k2].z;
                    acc[r][3] += aa[k2] * w0[k2].w;
                    acc[r][4] += aa[k2] * w1_[k2].x;
                    acc[r][5] += aa[k2] * w1_[k2].y;
                    acc[r][6] += aa[k2] * w1_[k2].z;
                    acc[r][7] += aa[k2] * w1_[k2].w;
                }
            }
        }
        const bool isq = (c0 < 96);
#pragma unroll
        for (int r = 0; r < 7; ++r)
#pragma unroll
            for (int c = 0; c < 8; ++c) {
                float v = acc[r][c] + qb[c0 + c];
                if (isq) v *= SCALE_;
                qkvs[r0 + r][c0 + c] = v;
            }
    }
    __syncthreads();

    if (tid < 147) {
        const int h = tid / 49, i = tid - h * 49;
        const int ih = i / 7, iw = i - ih * 7;
        const int qoff = h * 32, koff = 96 + h * 32, voff = 192 + h * 32;
        const int mylbl = lbl[i];

        float4 q4[8];
#pragma unroll
        for (int dd = 0; dd < 8; ++dd)
            q4[dd] = *reinterpret_cast<const float4*>(&qkvs[i][qoff + dd * 4]);

        float s[49];
#pragma unroll
        for (int j = 0; j < 49; ++j) {
            float acc = 0.f;
#pragma unroll
            for (int dd = 0; dd < 8; ++dd) {
                float4 k4 = *reinterpret_cast<const float4*>(&qkvs[j][koff + dd * 4]);
                acc += q4[dd].x * k4.x + q4[dd].y * k4.y
                     + q4[dd].z * k4.z + q4[dd].w * k4.w;
            }
            const int jh = j / 7, jw = j - jh * 7;
            const int ridx = (ih - jh + 6) * 13 + (iw - jw + 6);
            acc += rpb_lds[ridx * 3 + h];
            if (mylbl != lbl[j]) acc -= 100.f;
            s[j] = acc;
        }

        float mx = -1e30f;
#pragma unroll
        for (int j = 0; j < 49; ++j) mx = fmaxf(mx, s[j]);
        float sum = 0.f;
#pragma unroll
        for (int j = 0; j < 49; ++j) { float e = __expf(s[j] - mx); s[j] = e; sum += e; }
        const float inv = 1.f / sum;
#pragma unroll
        for (int j = 0; j < 49; ++j) s[j] *= inv;

        float4 o[8];
#pragma unroll
        for (int dd = 0; dd < 8; ++dd) o[dd] = make_float4(0.f, 0.f, 0.f, 0.f);
#pragma unroll
        for (int j = 0; j < 49; ++j) {
            const float sv = s[j];
#pragma unroll
            for (int dd = 0; dd < 8; ++dd) {
                float4 v4 = *reinterpret_cast<const float4*>(&qkvs[j][voff + dd * 4]);
                o[dd].x += sv * v4.x; o[dd].y += sv * v4.y;
                o[dd].z += sv * v4.z; o[dd].w += sv * v4.w;
            }
        }
#pragma unroll
        for (int dd = 0; dd < 8; ++dd)
            *reinterpret_cast<float4*>(&xn[i][h * 32 + dd * 4]) = o[dd];
    }
    __syncthreads();

    if (tid < 168) {
        const int ig = tid / 24, cg = tid - ig * 24;
        const int r0 = ig * 7, c0 = cg * 4;
        float acc[7][4];
#pragma unroll
        for (int r = 0; r < 7; ++r)
#pragma unroll
            for (int c = 0; c < 4; ++c) acc[r][c] = 0.f;
#pragma unroll 2
        for (int kk = 0; kk < 96; kk += 4) {
            float4 w[4];
#pragma unroll
            for (int k2 = 0; k2 < 4; ++k2)
                w[k2] = *reinterpret_cast<const float4*>(&pw[(kk + k2) * 96 + c0]);
#pragma unroll
            for (int r = 0; r < 7; ++r) {
                float4 a4 = *reinterpret_cast<const float4*>(&xn[r0 + r][kk]);
                float aa[4] = {a4.x, a4.y, a4.z, a4.w};
#pragma unroll
                for (int k2 = 0; k2 < 4; ++k2) {
                    acc[r][0] += aa[k2] * w[k2].x;
                    acc[r][1] += aa[k2] * w[k2].y;
                    acc[r][2] += aa[k2] * w[k2].z;
                    acc[r][3] += aa[k2] * w[k2].w;
                }
            }
        }
        float* ob = out + (size_t)b * (HW_ * C_);
#pragma unroll
        for (int r = 0; r < 7; ++r) {
            const int n = r0 + r;
            const int t = tok[n];
            const float* resid = xb + (size_t)t * 96 + c0;
            float* op = ob + (size_t)t * 96 + c0;
#pragma unroll
            for (int c = 0; c < 4; ++c)
                op[c] = acc[r][c] + pb[c0 + c] + resid[c];
        }
    }
}

// ---------------------------------------------------------------------------
// K2 (new): MFMA MLP. 64 rows/block, 4 waves, in-place on d_out.
// LN2 -> fc1 (mfma 16x16x32 bf16) -> gelu -> fc2 (mfma) -> +residual.
// LDS: A1 64x104 bf16 (13.3KB) + H 64x392 bf16 (50.2KB) = 63.5KB -> 2 blk/CU.
// ---------------------------------------------------------------------------
__global__ __launch_bounds__(256, 2) void k_mlp(
    const float* __restrict__ io_in,
    const float* __restrict__ lng, const float* __restrict__ lnb,
    const __bf16* __restrict__ wf1, const float* __restrict__ fb1,
    const __bf16* __restrict__ wf2, const float* __restrict__ fb2,
    float* __restrict__ io_out)
{
    __shared__ __bf16 A1[64][104];
    __shared__ __bf16 Hs[64][392];

    const int tid  = threadIdx.x;
    const int lane = tid & 63;
    const int w    = tid >> 6;
    const int l15  = lane & 15;
    const int lh   = lane >> 4;           // 0..3
    const int row0 = blockIdx.x * 64;

    // ---- LN2: 4 lanes per row, 64 rows ----
    {
        const int row = tid >> 2, q = tid & 3;
        const float* rp = io_in + (size_t)(row0 + row) * 96 + q * 24;
        float4 xv[6];
#pragma unroll
        for (int u = 0; u < 6; ++u)
            xv[u] = reinterpret_cast<const float4*>(rp)[u];
        float sum = 0.f, sq = 0.f;
#pragma unroll
        for (int u = 0; u < 6; ++u) {
            sum += xv[u].x + xv[u].y + xv[u].z + xv[u].w;
            sq  += xv[u].x * xv[u].x + xv[u].y * xv[u].y
                 + xv[u].z * xv[u].z + xv[u].w * xv[u].w;
        }
        sum += __shfl_xor(sum, 1); sq += __shfl_xor(sq, 1);
        sum += __shfl_xor(sum, 2); sq += __shfl_xor(sq, 2);
        const float m = sum * (1.f / 96.f);
        const float var = sq * (1.f / 96.f) - m * m;
        const float r = rsqrtf(var + 1e-5f);
        const int c0 = q * 24;
#pragma unroll
        for (int u = 0; u < 6; ++u) {
            const int c = c0 + u * 4;
            A1[row][c + 0] = (__bf16)((xv[u].x - m) * r * lng[c + 0] + lnb[c + 0]);
            A1[row][c + 1] = (__bf16)((xv[u].y - m) * r * lng[c + 1] + lnb[c + 1]);
            A1[row][c + 2] = (__bf16)((xv[u].z - m) * r * lng[c + 2] + lnb[c + 2]);
            A1[row][c + 3] = (__bf16)((xv[u].w - m) * r * lng[c + 3] + lnb[c + 3]);
        }
    }
    __syncthreads();

    // ---- fc1: (64x96)@(96x384). Wave w owns cols [w*96, w*96+96). ----
    f32x4 acc[4][6];
#pragma unroll
    for (int n = 0; n < 6; ++n) {
        const float bv = fb1[w * 96 + n * 16 + l15];
#pragma unroll
        for (int mt = 0; mt < 4; ++mt) {
            acc[mt][n][0] = bv; acc[mt][n][1] = bv;
            acc[mt][n][2] = bv; acc[mt][n][3] = bv;
        }
    }
#pragma unroll
    for (int kt = 0; kt < 3; ++kt) {
        bf16x8 a[4];
#pragma unroll
        for (int mt = 0; mt < 4; ++mt)
            a[mt] = *reinterpret_cast<const bf16x8*>(&A1[mt * 16 + l15][kt * 32 + lh * 8]);
#pragma unroll
        for (int n = 0; n < 6; ++n) {
            bf16x8 bfrag = *reinterpret_cast<const bf16x8*>(
                wf1 + ((size_t)((kt * 24 + w * 6 + n) * 64 + lane)) * 8);
#pragma unroll
            for (int mt = 0; mt < 4; ++mt)
                acc[mt][n] = __builtin_amdgcn_mfma_f32_16x16x32_bf16(
                    a[mt], bfrag, acc[mt][n], 0, 0, 0);
        }
    }

    // ---- gelu + store H (bf16) ----
#pragma unroll
    for (int mt = 0; mt < 4; ++mt)
#pragma unroll
        for (int n = 0; n < 6; ++n)
#pragma unroll
            for (int j = 0; j < 4; ++j) {
                const float g = gelu_fast(acc[mt][n][j]);
                Hs[mt * 16 + lh * 4 + j][w * 96 + n * 16 + l15] = (__bf16)g;
            }
    __syncthreads();

    // ---- fc2: (64x384)@(384x96). Wave w owns rows [w*16, w*16+16). ----
    f32x4 acc2[6];
#pragma unroll
    for (int n = 0; n < 6; ++n) {
        const float bv = fb2[n * 16 + l15];
        acc2[n][0] = bv; acc2[n][1] = bv; acc2[n][2] = bv; acc2[n][3] = bv;
    }
    const __bf16* hrow = &Hs[w * 16 + l15][0];

    bf16x8 a0 = *reinterpret_cast<const bf16x8*>(hrow + lh * 8);
    bf16x8 bc[6];
#pragma unroll
    for (int n = 0; n < 6; ++n)
        bc[n] = *reinterpret_cast<const bf16x8*>(wf2 + ((size_t)((0 * 6 + n) * 64 + lane)) * 8);

    for (int kt2 = 0; kt2 < 6; ++kt2) {
        const int k0 = kt2 * 2;
        bf16x8 a1 = *reinterpret_cast<const bf16x8*>(hrow + (k0 + 1) * 32 + lh * 8);
        bf16x8 bn[6];
#pragma unroll
        for (int n = 0; n < 6; ++n)
            bn[n] = *reinterpret_cast<const bf16x8*>(
                wf2 + ((size_t)(((k0 + 1) * 6 + n) * 64 + lane)) * 8);
#pragma unroll
        for (int n = 0; n < 6; ++n)
            acc2[n] = __builtin_amdgcn_mfma_f32_16x16x32_bf16(a0, bc[n], acc2[n], 0, 0, 0);
        if (kt2 < 5) {
            a0 = *reinterpret_cast<const bf16x8*>(hrow + (k0 + 2) * 32 + lh * 8);
#pragma unroll
            for (int n = 0; n < 6; ++n)
                bc[n] = *reinterpret_cast<const bf16x8*>(
                    wf2 + ((size_t)(((k0 + 2) * 6 + n) * 64 + lane)) * 8);
        }
#pragma unroll
        for (int n = 0; n < 6; ++n)
            acc2[n] = __builtin_amdgcn_mfma_f32_16x16x32_bf16(a1, bn[n], acc2[n], 0, 0, 0);
    }

    // ---- epilogue: + residual (fp32), write out ----
#pragma unroll
    for (int n = 0; n < 6; ++n)
#pragma unroll
        for (int j = 0; j < 4; ++j) {
            const int row = row0 + w * 16 + lh * 4 + j;
            const int col = n * 16 + l15;
            const size_t off = (size_t)row * 96 + col;
            io_out[off] = acc2[n][j] + io_in[off];
        }
}

extern "C" void kernel_launch(void* const* d_in, const int* in_sizes, int n_in,
                              void* d_out, int out_size, void* d_ws, size_t ws_size,
                              hipStream_t stream) {
    const float* x   = (const float*)d_in[0];
    const float* g1  = (const float*)d_in[1];
    const float* b1  = (const float*)d_in[2];
    const float* qw  = (const float*)d_in[3];
    const float* qb  = (const float*)d_in[4];
    const float* rpb = (const float*)d_in[5];
    const float* pw  = (const float*)d_in[6];
    const float* pb  = (const float*)d_in[7];
    const float* g2  = (const float*)d_in[8];
    const float* b2  = (const float*)d_in[9];
    const float* w1  = (const float*)d_in[10];
    const float* bb1 = (const float*)d_in[11];
    const float* w2  = (const float*)d_in[12];
    const float* bb2 = (const float*)d_in[13];
    float* out = (float*)d_out;

    __bf16* wsb = (__bf16*)d_ws;          // [0,36864): W1 frags; [36864,73728): W2 frags

    hipLaunchKernelGGL(k_cvt, dim3(36), dim3(256), 0, stream, w1, w2, wsb);
    hipLaunchKernelGGL(k_attn, dim3(8192), dim3(256), 0, stream,
                       x, g1, b1, qw, qb, rpb, pw, pb, out);
    hipLaunchKernelGGL(k_mlp, dim3(6272), dim3(256), 0, stream,
                       out, g2, b2, wsb, bb1, wsb + 36864, bb2, out);
}